// Round 1
// baseline (1096.898 us; speedup 1.0000x reference)
//
#include <hip/hip_runtime.h>

typedef __attribute__((ext_vector_type(8))) short short8;
typedef __attribute__((ext_vector_type(4))) float f32x4;

__device__ __forceinline__ unsigned short f2bf(float f) {
    unsigned u = __float_as_uint(f);
    u += 0x7fffu + ((u >> 16) & 1u);
    return (unsigned short)(u >> 16);
}

// Fused prep: block ranges
//   [0,2048)    : queries fp32 (first 512 cols) -> Qh bf16 [b,h,n,64], scaled 1/8
//   [2048,2560) : gate(keys)   -> Kh [b,h,n,64]
//   [2560,3072) : gate(values) -> Vt [b,h,d,2048] (transposed in LDS epilogue)
//   [3072,3328) : c[j] = bo[j] + sum_i Wo[j,512+i]*v_sum[i]
//   [3328,3456) : Wo[:,0:512] -> Wob bf16 [1024][512]
__global__ __launch_bounds__(256) void k_prep(
        const float* __restrict__ queries,
        const float* __restrict__ keys, const float* __restrict__ values,
        const float* __restrict__ Wk_f, const float* __restrict__ bk_f, const float* __restrict__ kf_bias,
        const float* __restrict__ Wv_f, const float* __restrict__ bv_f, const float* __restrict__ vf_bias,
        const float* __restrict__ Wo, const float* __restrict__ bo, const float* __restrict__ vsum,
        unsigned short* __restrict__ Qh, unsigned short* __restrict__ Kh,
        unsigned short* __restrict__ Vt, unsigned short* __restrict__ Wob,
        float* __restrict__ cvec) {
    __shared__ __align__(16) unsigned short SMEM[11264];  // Xs[64*88] + Wsh[64*88]
    int bx = blockIdx.x;
    int t = threadIdx.x;

    if (bx < 2048) {
        // ---- convq ----
        int e = (bx * 256 + t) * 4;
        int c = e & 511;
        int bn = e >> 9;
        float4 v = *reinterpret_cast<const float4*>(queries + (size_t)bn * 1024 + c);
        int h = c >> 6, d = c & 63;
        int b = bn >> 11, n = bn & 2047;
        ushort4 o;
        o.x = f2bf(v.x * 0.125f); o.y = f2bf(v.y * 0.125f);
        o.z = f2bf(v.z * 0.125f); o.w = f2bf(v.w * 0.125f);
        *reinterpret_cast<ushort4*>(Qh + (((size_t)(b*8+h) * 2048 + n) * 64 + d)) = o;
    } else if (bx < 3072) {
        // ---- gate GEMM, 64x64 tile, reg-staged double buffer ----
        bool isK = bx < 2560;
        int local = bx - (isK ? 2048 : 2560);
        int mb = local & 63, by = local >> 6;
        const float* X  = isK ? keys : values;
        const float* W  = isK ? Wk_f : Wv_f;
        const float* b1 = isK ? bk_f : bv_f;
        const float* b2 = isK ? kf_bias : vf_bias;
        unsigned short* Xs  = SMEM;
        unsigned short* Wsh = SMEM + 5632;
        int mbase = mb * 64, nbase = by * 64;
        int w = t >> 6, lane = t & 63, l = lane & 15, quad = lane >> 4;
        int srow = t >> 2, sk = (t & 3) * 16;
        const float* Xrow = X + (size_t)(mbase + srow) * 1024 + sk;
        const float* Wrow = W + (size_t)(nbase + srow) * 1024 + sk;
        float4 xr[4], wr[4];
        #pragma unroll
        for (int i = 0; i < 4; ++i) {
            xr[i] = *reinterpret_cast<const float4*>(Xrow + i*4);
            wr[i] = *reinterpret_cast<const float4*>(Wrow + i*4);
        }
        f32x4 acc[4] = {};
        for (int kk = 0; kk < 1024; kk += 64) {
            #pragma unroll
            for (int i = 0; i < 4; ++i) {
                float4 xv = xr[i], wv = wr[i];
                ushort4 xo, wo;
                xo.x=f2bf(xv.x); xo.y=f2bf(xv.y); xo.z=f2bf(xv.z); xo.w=f2bf(xv.w);
                wo.x=f2bf(wv.x); wo.y=f2bf(wv.y); wo.z=f2bf(wv.z); wo.w=f2bf(wv.w);
                *reinterpret_cast<ushort4*>(&Xs[srow*88 + sk + i*4]) = xo;
                *reinterpret_cast<ushort4*>(&Wsh[srow*88 + sk + i*4]) = wo;
            }
            __syncthreads();
            if (kk + 64 < 1024) {  // prefetch next k-chunk under MFMA
                #pragma unroll
                for (int i = 0; i < 4; ++i) {
                    xr[i] = *reinterpret_cast<const float4*>(Xrow + kk + 64 + i*4);
                    wr[i] = *reinterpret_cast<const float4*>(Wrow + kk + 64 + i*4);
                }
            }
            short8 a0 = *reinterpret_cast<const short8*>(&Xs[(w*16+l)*88 + quad*8]);
            short8 a1 = *reinterpret_cast<const short8*>(&Xs[(w*16+l)*88 + 32 + quad*8]);
            #pragma unroll
            for (int nt = 0; nt < 4; ++nt) {
                short8 bq0 = *reinterpret_cast<const short8*>(&Wsh[(l+16*nt)*88 + quad*8]);
                short8 bq1 = *reinterpret_cast<const short8*>(&Wsh[(l+16*nt)*88 + 32 + quad*8]);
                acc[nt] = __builtin_amdgcn_mfma_f32_16x16x32_bf16(a0, bq0, acc[nt], 0, 0, 0);
                acc[nt] = __builtin_amdgcn_mfma_f32_16x16x32_bf16(a1, bq1, acc[nt], 0, 0, 0);
            }
            __syncthreads();
        }
        if (isK) {
            #pragma unroll
            for (int nt = 0; nt < 4; ++nt) {
                int col = nbase + l + 16*nt;
                float bias = b1[col] + b2[col];
                #pragma unroll
                for (int reg = 0; reg < 4; ++reg) {
                    int m = mbase + w*16 + quad*4 + reg;
                    float x = acc[nt][reg] + bias;
                    float g = 1.0f / (1.0f + __expf(-x));
                    int bb = m >> 11, n = m & 2047;
                    int hh = col >> 6, d = col & 63;
                    Kh[(((size_t)(bb*8+hh)*2048 + n)*64 + d)] = f2bf(g);
                }
            }
        } else {
            // transpose epilogue: stage bf16 tile in LDS, write Vt coalesced along n
            unsigned short* Ts = SMEM;  // [64][72], reuse (loop ended with barrier)
            #pragma unroll
            for (int nt = 0; nt < 4; ++nt) {
                int col = nbase + l + 16*nt;
                float bias = b1[col] + b2[col];
                #pragma unroll
                for (int reg = 0; reg < 4; ++reg) {
                    float x = acc[nt][reg] + bias;
                    float g = 1.0f / (1.0f + __expf(-x));
                    Ts[(w*16 + quad*4 + reg)*72 + (l + 16*nt)] = f2bf(g);
                }
            }
            __syncthreads();
            int d = t >> 2, c4 = (t & 3) * 16;
            unsigned short tmp[16];
            #pragma unroll
            for (int j = 0; j < 16; ++j) tmp[j] = Ts[(c4 + j)*72 + d];
            int bb = mbase >> 11, n0 = mbase & 2047;
            unsigned short* dst = Vt + ((size_t)(bb*8+by)*64 + d)*2048 + n0 + c4;
            *reinterpret_cast<short8*>(dst)     = *reinterpret_cast<short8*>(&tmp[0]);
            *reinterpret_cast<short8*>(dst + 8) = *reinterpret_cast<short8*>(&tmp[8]);
        }
    } else if (bx < 3328) {
        // ---- compute_c ----
        int w = t >> 6, lane = t & 63;
        int j = (bx - 3072) * 4 + w;
        const float* row = Wo + (size_t)j * 1024 + 512;
        float acc = 0.0f;
        #pragma unroll
        for (int i = 0; i < 8; ++i) acc = fmaf(row[lane + 64*i], vsum[lane + 64*i], acc);
        #pragma unroll
        for (int off = 32; off; off >>= 1) acc += __shfl_xor(acc, off);
        if (lane == 0) cvec[j] = acc + bo[j];
    } else {
        // ---- Wo[:,0:512] -> bf16 ----
        int base = ((bx - 3328) * 256 + t) * 16;
        int row = base >> 9, col = base & 511;
        const float4* src = reinterpret_cast<const float4*>(Wo + (size_t)row * 1024 + col);
        #pragma unroll
        for (int i = 0; i < 4; ++i) {
            float4 v = src[i];
            ushort4 o;
            o.x=f2bf(v.x); o.y=f2bf(v.y); o.z=f2bf(v.z); o.w=f2bf(v.w);
            *reinterpret_cast<ushort4*>(Wob + base + i*4) = o;
        }
    }
}

// Flash attention, heads 0..7. Barrier-free waves + split-K x2. (unchanged)
#define NEGBIG -1e30f
__global__ __launch_bounds__(256) void k_attn(const unsigned short* __restrict__ Qh,
        const unsigned short* __restrict__ Kh, const unsigned short* __restrict__ Vt,
        const float* __restrict__ attw, const int* __restrict__ mask,
        unsigned short* __restrict__ O) {
    __shared__ __align__(16) unsigned short Ps[4*16*88];
    __shared__ __align__(16) float Og[2][16*64];
    __shared__ float Ml[2][2][16];
    int bx = blockIdx.x;
    int qt = bx & 63, h = (bx >> 6) & 7, b = bx >> 9;
    int t = threadIdx.x, w = t >> 6, lane = t & 63, l = lane & 15, quad = lane >> 4;
    int qgrp = w >> 1, kh = w & 1;
    int qbase = qt * 32 + qgrp * 16;
    int bh = b*8 + h;
    const unsigned short* qp = Qh + ((size_t)bh*2048 + qbase + l)*64 + quad*8;
    short8 qf0 = *reinterpret_cast<const short8*>(qp);
    short8 qf1 = *reinterpret_cast<const short8*>(qp + 32);
    float m_r[4], l_r[4];
    f32x4 oacc[4] = {};
    #pragma unroll
    for (int r = 0; r < 4; ++r) { m_r[r] = NEGBIG; l_r[r] = 0.0f; }
    unsigned short* Pw = &Ps[w * 16*88];
    const size_t fbase = ((size_t)((b*16 + h)*2048 + qbase + quad*4))*2048 + l;
    const int khbase = kh * 1024;

    float awA[16], awB[16];
    int   mkA[16], mkB[16];

    #pragma unroll
    for (int reg = 0; reg < 4; ++reg)
        #pragma unroll
        for (int nt = 0; nt < 4; ++nt) {
            size_t off = fbase + (size_t)reg*2048 + khbase + 16*nt;
            awA[reg*4+nt] = attw[off];
            mkA[reg*4+nt] = mask[off];
        }

    auto body = [&](int kbase, float* awc, int* mkc, float* awn, int* mkn, bool pref) {
        if (pref) {
            #pragma unroll
            for (int reg = 0; reg < 4; ++reg)
                #pragma unroll
                for (int nt = 0; nt < 4; ++nt) {
                    size_t off = fbase + (size_t)reg*2048 + (kbase + 64) + 16*nt;
                    awn[reg*4+nt] = attw[off];
                    mkn[reg*4+nt] = mask[off];
                }
        }
        f32x4 s[4] = {};
        #pragma unroll
        for (int nt = 0; nt < 4; ++nt) {
            const unsigned short* kp = Kh + ((size_t)bh*2048 + kbase + l + 16*nt)*64 + quad*8;
            short8 k0 = *reinterpret_cast<const short8*>(kp);
            short8 k1 = *reinterpret_cast<const short8*>(kp + 32);
            s[nt] = __builtin_amdgcn_mfma_f32_16x16x32_bf16(qf0, k0, s[nt], 0, 0, 0);
            s[nt] = __builtin_amdgcn_mfma_f32_16x16x32_bf16(qf1, k1, s[nt], 0, 0, 0);
        }
        float sv[4][4];
        #pragma unroll
        for (int reg = 0; reg < 4; ++reg)
            #pragma unroll
            for (int nt = 0; nt < 4; ++nt)
                sv[nt][reg] = mkc[reg*4+nt] ? NEGBIG : s[nt][reg] * awc[reg*4+nt];
        float alpha[4];
        #pragma unroll
        for (int reg = 0; reg < 4; ++reg) {
            float rm = fmaxf(fmaxf(sv[0][reg], sv[1][reg]), fmaxf(sv[2][reg], sv[3][reg]));
            rm = fmaxf(rm, __shfl_xor(rm, 1));
            rm = fmaxf(rm, __shfl_xor(rm, 2));
            rm = fmaxf(rm, __shfl_xor(rm, 4));
            rm = fmaxf(rm, __shfl_xor(rm, 8));
            float mnew = fmaxf(m_r[reg], rm);
            alpha[reg] = __expf(m_r[reg] - mnew);
            m_r[reg] = mnew;
            float rs = 0.0f;
            #pragma unroll
            for (int nt = 0; nt < 4; ++nt) {
                float p = __expf(sv[nt][reg] - mnew);
                sv[nt][reg] = p;
                rs += p;
            }
            rs += __shfl_xor(rs, 1);
            rs += __shfl_xor(rs, 2);
            rs += __shfl_xor(rs, 4);
            rs += __shfl_xor(rs, 8);
            l_r[reg] = l_r[reg] * alpha[reg] + rs;
        }
        #pragma unroll
        for (int dt = 0; dt < 4; ++dt)
            #pragma unroll
            for (int reg = 0; reg < 4; ++reg)
                oacc[dt][reg] *= alpha[reg];
        #pragma unroll
        for (int reg = 0; reg < 4; ++reg)
            #pragma unroll
            for (int nt = 0; nt < 4; ++nt)
                Pw[(quad*4+reg)*88 + l + 16*nt] = f2bf(sv[nt][reg]);
        __builtin_amdgcn_s_waitcnt(0xC07F);  // lgkmcnt(0)
        short8 pf0 = *reinterpret_cast<const short8*>(&Pw[l*88 + quad*8]);
        short8 pf1 = *reinterpret_cast<const short8*>(&Pw[l*88 + 32 + quad*8]);
        #pragma unroll
        for (int dt = 0; dt < 4; ++dt) {
            const unsigned short* vp = Vt + ((size_t)bh*64 + l + 16*dt)*2048 + kbase + quad*8;
            short8 v0 = *reinterpret_cast<const short8*>(vp);
            short8 v1 = *reinterpret_cast<const short8*>(vp + 32);
            oacc[dt] = __builtin_amdgcn_mfma_f32_16x16x32_bf16(pf0, v0, oacc[dt], 0, 0, 0);
            oacc[dt] = __builtin_amdgcn_mfma_f32_16x16x32_bf16(pf1, v1, oacc[dt], 0, 0, 0);
        }
    };

    for (int i = 0; i < 8; ++i) {
        body(khbase + (2*i)*64,   awA, mkA, awB, mkB, true);
        body(khbase + (2*i+1)*64, awB, mkB, awA, mkA, i < 7);
    }

    if (kh == 1) {
        #pragma unroll
        for (int dt = 0; dt < 4; ++dt)
            #pragma unroll
            for (int reg = 0; reg < 4; ++reg)
                Og[qgrp][(quad*4+reg)*64 + l + 16*dt] = oacc[dt][reg];
        if (l == 0) {
            #pragma unroll
            for (int reg = 0; reg < 4; ++reg) {
                Ml[qgrp][0][quad*4+reg] = m_r[reg];
                Ml[qgrp][1][quad*4+reg] = l_r[reg];
            }
        }
    }
    __syncthreads();
    if (kh == 0) {
        #pragma unroll
        for (int reg = 0; reg < 4; ++reg) {
            int row = quad*4 + reg;
            float m1 = Ml[qgrp][0][row];
            float l1 = Ml[qgrp][1][row];
            float mstar = fmaxf(m_r[reg], m1);
            float a0 = __expf(m_r[reg] - mstar);
            float a1 = __expf(m1 - mstar);
            float inv = 1.0f / (l_r[reg]*a0 + l1*a1);
            int qr = qbase + row;
            #pragma unroll
            for (int dt = 0; dt < 4; ++dt) {
                float v1 = Og[qgrp][row*64 + l + 16*dt];
                float val = (oacc[dt][reg]*a0 + v1*a1) * inv;
                O[((size_t)b*2048 + qr)*512 + h*64 + l + 16*dt] = f2bf(val);
            }
        }
    }
}

// out[m,n] = sum_{k<512} O[m,k]*Wob[n,k] + c[n]  — LDS/barrier-free, bf16 weights
__global__ __launch_bounds__(256) void k_proj(const unsigned short* __restrict__ O,
        const unsigned short* __restrict__ Wob, const float* __restrict__ c, float* __restrict__ out) {
    int t = threadIdx.x;
    int mb = blockIdx.x * 64, nb = blockIdx.y * 64;
    int w = t >> 6, lane = t & 63, l = lane & 15, quad = lane >> 4;
    const unsigned short* op = O + (size_t)(mb + w*16 + l)*512 + quad*8;
    const unsigned short* wp = Wob + (size_t)(nb + l)*512 + quad*8;
    f32x4 acc[4] = {};
    for (int kb = 0; kb < 512; kb += 64) {
        short8 a0 = *reinterpret_cast<const short8*>(op + kb);
        short8 a1 = *reinterpret_cast<const short8*>(op + kb + 32);
        #pragma unroll
        for (int nt = 0; nt < 4; ++nt) {
            short8 b0 = *reinterpret_cast<const short8*>(wp + nt*16*512 + kb);
            short8 b1 = *reinterpret_cast<const short8*>(wp + nt*16*512 + kb + 32);
            acc[nt] = __builtin_amdgcn_mfma_f32_16x16x32_bf16(a0, b0, acc[nt], 0, 0, 0);
            acc[nt] = __builtin_amdgcn_mfma_f32_16x16x32_bf16(a1, b1, acc[nt], 0, 0, 0);
        }
    }
    #pragma unroll
    for (int nt = 0; nt < 4; ++nt) {
        int coln = nb + l + 16*nt;
        float cv = c[coln];
        #pragma unroll
        for (int reg = 0; reg < 4; ++reg) {
            int row = mb + w*16 + quad*4 + reg;
            out[(size_t)row*1024 + coln] = acc[nt][reg] + cv;
        }
    }
}

extern "C" void kernel_launch(void* const* d_in, const int* in_sizes, int n_in,
                              void* d_out, int out_size, void* d_ws, size_t ws_size,
                              hipStream_t stream) {
    const float* queries = (const float*)d_in[0];
    const float* keys    = (const float*)d_in[1];
    const float* values  = (const float*)d_in[2];
    const int*   mask    = (const int*)d_in[3];
    const float* attw    = (const float*)d_in[4];
    const float* Wk_f    = (const float*)d_in[5];
    const float* bk_f    = (const float*)d_in[6];
    const float* kf_bias = (const float*)d_in[7];
    const float* Wv_f    = (const float*)d_in[8];
    const float* bv_f    = (const float*)d_in[9];
    const float* vf_bias = (const float*)d_in[10];
    // d_in[11] = k_sum: unused (heads>=8 output is exactly v_sum)
    const float* v_sum   = (const float*)d_in[12];
    const float* Wo      = (const float*)d_in[13];
    const float* bo      = (const float*)d_in[14];
    float* out = (float*)d_out;

    char* ws = (char*)d_ws;
    float* cvec = (float*)ws;                                   // 4 KB
    unsigned short* Qh  = (unsigned short*)(ws + 4096);         // 4 MB
    unsigned short* Kh  = Qh + (size_t)2*8*2048*64;             // 4 MB
    unsigned short* Vt  = Kh + (size_t)2*8*2048*64;             // 4 MB
    unsigned short* Ob  = Vt + (size_t)2*8*2048*64;             // 4 MB
    unsigned short* Wob = Ob + (size_t)2*8*2048*64;             // 1 MB

    hipLaunchKernelGGL(k_prep, dim3(3456), dim3(256), 0, stream,
        queries, keys, values, Wk_f, bk_f, kf_bias, Wv_f, bv_f, vf_bias,
        Wo, bo, v_sum, Qh, Kh, Vt, Wob, cvec);
    hipLaunchKernelGGL(k_attn, dim3(1024), dim3(256), 0, stream, Qh, Kh, Vt, attw, mask, Ob);
    hipLaunchKernelGGL(k_proj, dim3(64, 16), dim3(256), 0, stream, Ob, Wob, cvec, out);
}